// Round 12
// baseline (108.849 us; speedup 1.0000x reference)
//
#include <hip/hip_runtime.h>

// B=8, G=3, IN=384, OUT=384, H=64, W=64, CG=128, OG=128
// R12: R11 (LDS-window gather) with the fill-loop bug FIXED: each cached
// cell is 128 shorts = 16 sixteen-byte slices (R11 filled only 8 -> channels
// 64..127 were uninitialized LDS -> NaN). Numerics identical to R8
// (bf16 xT, fp32 blend, fp16 weight table, validated bf16 MFMA layout).
// All 9 taps gather from a 7x38 LDS window at fixed immediate offsets:
// kills the VMEM gather (L1-return ~45% of cycles in R4-R8).

typedef __attribute__((ext_vector_type(8))) short short8;
typedef __attribute__((ext_vector_type(4))) float floatx4;
typedef __attribute__((ext_vector_type(4))) unsigned int uintx4;

#define SLAB 524288            // 64*64*128 shorts per (b,g)
#define ROWS 7                 // cached rows: clamp(h-3 .. h+3)
#define COLS 38                // cached cols: clamp(pos0-3 .. pos0+34)
#define ROWSTRIDE (COLS * 128) // 4864 shorts

__device__ __forceinline__ float bf_lo(unsigned int d) {
  return __uint_as_float(d << 16);
}
__device__ __forceinline__ float bf_hi(unsigned int d) {
  return __uint_as_float(d & 0xffff0000u);
}
__device__ __forceinline__ unsigned int cvtpk_bf16(float lo, float hi) {
  unsigned int r;
  asm("v_cvt_pk_bf16_f32 %0, %1, %2" : "=v"(r) : "v"(lo), "v"(hi));
  return r;
}
__device__ __forceinline__ ushort f2h(float x) {
  _Float16 h = (_Float16)x;
  return __builtin_bit_cast(ushort, h);
}
__device__ __forceinline__ float h2f(ushort u) {
  return (float)__builtin_bit_cast(_Float16, u);
}

// ---------------------------------------------------------------------------
// Kernel 1: NCHW fp32 -> (b,g,y,x,c) bf16, c contiguous (128)
// ---------------------------------------------------------------------------
__global__ __launch_bounds__(256) void transpose_x_kernel(
    const float* __restrict__ in, ushort* __restrict__ xT) {
  __shared__ float tile[32][33];
  const int t  = threadIdx.x;
  const int tx = t & 31, ty = t >> 5;      // 32 x 8
  const int bx = blockIdx.x;               // x-tile (2) x c-tile (4)
  const int x0 = (bx & 1) * 32;
  const int c0 = (bx >> 1) * 32;
  const int y  = blockIdx.y;
  const int bg = blockIdx.z;
  const int b  = bg / 3, g = bg % 3;

  const float* src = in + ((size_t)(b * 384 + g * 128)) * 4096 + (size_t)y * 64;
#pragma unroll
  for (int it = 0; it < 4; ++it) {
    int c = c0 + ty + it * 8;
    tile[ty + it * 8][tx] = src[(size_t)c * 4096 + x0 + tx];
  }
  __syncthreads();
  ushort* dst = xT + (((size_t)bg * 64 + y) * 64) * 128;
#pragma unroll
  for (int it = 0; it < 4; ++it) {
    int x = x0 + ty + it * 8;
    float v = tile[tx][ty + it * 8];
    dst[(size_t)x * 128 + c0 + tx] =
        (ushort)((__float_as_uint(v) + 0x8000u) >> 16);
  }
}

// ---------------------------------------------------------------------------
// Kernel 2: w_d (OUT, CG, 3, 3) fp32 -> bf16 A-fragment order (VALIDATED):
//   wB[(((g*9+k)*4+s)*8+f)*64+l][j] = w[g][o=f*16+(l&15)][c=s*32+(l>>4)*8+j]
// ---------------------------------------------------------------------------
__global__ __launch_bounds__(256) void swizzle_w_kernel(
    const float* __restrict__ w_d, ushort* __restrict__ wB) {
  int idx = blockIdx.x * 256 + threadIdx.x;  // 442368 total
  if (idx >= 442368) return;
  int j  = idx & 7;
  int l  = (idx >> 3) & 63;
  int f  = (idx >> 9) & 7;
  int s  = (idx >> 12) & 3;
  int t2 = idx >> 14;            // g*9 + k
  int k  = t2 % 9;
  int g  = t2 / 9;
  int o  = f * 16 + (l & 15);
  int c  = s * 32 + (l >> 4) * 8 + j;
  float v = w_d[((size_t)(g * 128 + o) * 128 + c) * 9 + k];
  wB[idx] = (ushort)((__float_as_uint(v) + 0x8000u) >> 16);
}

// ---------------------------------------------------------------------------
// Kernel 3: main fused kernel. 3072 blocks, XCD-swizzled: b = bid&7.
// Block = (b,g,h,ph): 32 positions x 128 out-chans, 4 waves.
// ---------------------------------------------------------------------------
__global__ __launch_bounds__(256) void fa_main_mfma(
    const ushort* __restrict__ xT, const ushort* __restrict__ wB,
    const float* __restrict__ wh_pred, const float* __restrict__ w_off,
    const float* __restrict__ b_off, const float* __restrict__ b_d,
    float* __restrict__ out) {
  __shared__ __align__(16) ushort xrow[ROWS * COLS * 128];  // 68096 B
  __shared__ int     off_s[9][32];
  __shared__ ushort4 w4h_s[9][32];      // fp16 bilinear weights (proven R8)
  __shared__ ushort  samp[32][128];     // bf16, XOR-swizzled (proven R7)

  const int t   = threadIdx.x;
  const int bid = blockIdx.x;
  const int b   = bid & 7;          // XCD-pinned batch image
  const int rem = bid >> 3;         // (g*64 + h)*2 + ph
  const int ph  = rem & 1;
  const int h   = (rem >> 1) & 63;
  const int g   = rem >> 7;
  const int pos0 = ph * 32;

  const ushort* xb = xT + (size_t)(b * 3 + g) * SLAB;
  const ushort* wg = wB + (size_t)g * 9 * 16384;

  // --- fill the 7x38 clamped window: xrow[r][j][c] = xT[clamp rows/cols] ---
  // Each cell = 128 shorts = SIXTEEN 16B slices (R11 bug: used 8 -> NaN).
  for (int it = 0; it < 17; ++it) {
    int idx = it * 256 + t;                 // 16B slices: 7*38*16 = 4256
    if (idx < ROWS * COLS * 16) {
      int r    = idx / (COLS * 16);
      int rem2 = idx - r * (COLS * 16);
      int j    = rem2 >> 4;
      int c16  = rem2 & 15;
      int yg = min(max(h - 3 + r, 0), 63);
      int xg = min(max(pos0 - 3 + j, 0), 63);
      *(uintx4*)&xrow[(r * COLS + j) * 128 + c16 * 8] =
          *(const uintx4*)(xb + ((size_t)(yg * 64 + xg)) * 128 + c16 * 8);
    }
  }

  // --- prologue: per (tap,pos) bilinear weights + cache-cell offset --------
  for (int idx = t; idx < 288; idx += 256) {
    int k = idx >> 5, pos = idx & 31;
    int posg = pos0 + pos;
    float wh0 = wh_pred[(((size_t)b * 6 + g * 2 + 0) * 64 + h) * 64 + posg];
    float wh1 = wh_pred[(((size_t)b * 6 + g * 2 + 1) * 64 + h) * 64 + posg];
    int oy_i = g * 18 + k * 2;
    int ox_i = oy_i + 1;
    float oy = fmaf(w_off[oy_i * 2], wh0, fmaf(w_off[oy_i * 2 + 1], wh1, b_off[oy_i]));
    float ox = fmaf(w_off[ox_i * 2], wh0, fmaf(w_off[ox_i * 2 + 1], wh1, b_off[ox_i]));
    float py = oy + (float)(h + k / 3 - 1);
    float px = ox + (float)(posg + k % 3 - 1);

    float fy = floorf(py), fx = floorf(px);
    int y0 = (int)fy, x0 = (int)fx;
    float wy = py - fy, wx = px - fx;
    float m_y0 = ((unsigned)y0 < 64u) ? 1.f : 0.f;
    float m_y1 = ((unsigned)(y0 + 1) < 64u) ? 1.f : 0.f;
    float m_x0 = ((unsigned)x0 < 64u) ? 1.f : 0.f;
    float m_x1 = ((unsigned)(x0 + 1) < 64u) ? 1.f : 0.f;
    ushort4 w4;
    w4.x = f2h((1.f - wy) * (1.f - wx) * m_y0 * m_x0);
    w4.y = f2h((1.f - wy) * wx * m_y0 * m_x1);
    w4.z = f2h(wy * (1.f - wx) * m_y1 * m_x0);
    w4.w = f2h(wy * wx * m_y1 * m_x1);
    // cache cell: row i = y0-(h-3), col j = x0-(pos0-3); clamped cache
    // rows/cols make clamped lookups automatic; masks zero all truly-OOB
    // corners (same semantics as R8's global clamp+guard).
    int i = min(max(y0 - h + 3, 0), 5);
    int j = min(max(x0 - pos0 + 3, 0), 36);
    off_s[k][pos] = (i * COLS + j) * 128;
    w4h_s[k][pos] = w4;
  }
  __syncthreads();

  const int wv  = t >> 6;   // wave 0..3
  const int l   = t & 63;
  const int l15 = l & 15;
  const int lhi = l >> 4;   // 0..3

  floatx4 acc[2][2];
#pragma unroll
  for (int ia = 0; ia < 2; ++ia) {
#pragma unroll
    for (int r = 0; r < 4; ++r) {
      float bias = b_d[g * 128 + wv * 32 + ia * 16 + lhi * 4 + r];
#pragma unroll
      for (int jb = 0; jb < 2; ++jb) acc[ia][jb][r] = bias;
    }
  }

  // staging: 16 lanes per position (contiguous 16B each), 2 passes of 16 pos
  const int g16    = t >> 4;   // 0..15: position group
  const int lane16 = t & 15;   // 0..15: 16B slice of the 256B channel row

  auto stage = [&](int k) {
#pragma unroll
    for (int p = 0; p < 2; ++p) {
      int pos = p * 16 + g16;
      int base = off_s[k][pos] + lane16 * 8;
      ushort4 wq = w4h_s[k][pos];
      float w00 = h2f(wq.x), w01 = h2f(wq.y), w10 = h2f(wq.z), w11 = h2f(wq.w);
      // corners at fixed LDS offsets: +0, +128, +ROWSTRIDE, +ROWSTRIDE+128
      uintx4 a00 = *(const uintx4*)&xrow[base];
      uintx4 a01 = *(const uintx4*)&xrow[base + 128];
      uintx4 a10 = *(const uintx4*)&xrow[base + ROWSTRIDE];
      uintx4 a11 = *(const uintx4*)&xrow[base + ROWSTRIDE + 128];
      uintx4 pk;
#pragma unroll
      for (int d = 0; d < 4; ++d) {
        float lo = fmaf(bf_lo(a11[d]), w11, fmaf(bf_lo(a10[d]), w10,
                   fmaf(bf_lo(a01[d]), w01, bf_lo(a00[d]) * w00)));
        float hi = fmaf(bf_hi(a11[d]), w11, fmaf(bf_hi(a10[d]), w10,
                   fmaf(bf_hi(a01[d]), w01, bf_hi(a00[d]) * w00)));
        pk[d] = cvtpk_bf16(lo, hi);
      }
      *(uintx4*)&samp[pos][(lane16 * 8) ^ ((pos & 7) << 3)] = pk;
    }
  };

  auto mfma_phase = [&](int k) {
    const ushort* wk = wg + (size_t)k * 16384;
#pragma unroll
    for (int s = 0; s < 4; ++s) {
      short8 a0 = *(const short8*)(wk + ((s * 8 + wv * 2 + 0) * 64 + l) * 8);
      short8 a1 = *(const short8*)(wk + ((s * 8 + wv * 2 + 1) * 64 + l) * 8);
      const int cb = (s * 32 + lhi * 8) ^ ((l15 & 7) << 3);
#pragma unroll
      for (int jb = 0; jb < 2; ++jb) {
        short8 bf = *(const short8*)&samp[jb * 16 + l15][cb];
        acc[0][jb] = __builtin_amdgcn_mfma_f32_16x16x32_bf16(a0, bf, acc[0][jb], 0, 0, 0);
        acc[1][jb] = __builtin_amdgcn_mfma_f32_16x16x32_bf16(a1, bf, acc[1][jb], 0, 0, 0);
      }
    }
  };

  // --- tap loop: single samp buffer, 2 barriers per tap (R4-proven) --------
  for (int k = 0; k < 9; ++k) {
    stage(k);
    __syncthreads();
    mfma_phase(k);
    __syncthreads();
  }

  // --- store: out (B, 384, H, W); C col(lane&15) = pos = contiguous W -------
#pragma unroll
  for (int ia = 0; ia < 2; ++ia) {
#pragma unroll
    for (int jb = 0; jb < 2; ++jb) {
#pragma unroll
      for (int r = 0; r < 4; ++r) {
        int o = wv * 32 + ia * 16 + lhi * 4 + r;
        int pos = pos0 + jb * 16 + l15;
        out[(((size_t)(b * 384 + g * 128 + o)) * 64 + h) * 64 + pos] = acc[ia][jb][r];
      }
    }
  }
}

extern "C" void kernel_launch(void* const* d_in, const int* in_sizes, int n_in,
                              void* d_out, int out_size, void* d_ws, size_t ws_size,
                              hipStream_t stream) {
  const float* input   = (const float*)d_in[0];
  const float* wh_pred = (const float*)d_in[1];
  const float* w_off   = (const float*)d_in[2];
  const float* b_off   = (const float*)d_in[3];
  const float* w_d     = (const float*)d_in[4];
  const float* b_d     = (const float*)d_in[5];
  float* out = (float*)d_out;

  ushort* xT = (ushort*)d_ws;                       // 24*SLAB bf16 = 25.2 MB
  ushort* wB = xT + (size_t)24 * SLAB;              // 442368 bf16 = 0.88 MB

  transpose_x_kernel<<<dim3(8, 64, 24), 256, 0, stream>>>(input, xT);
  swizzle_w_kernel<<<dim3(1728), 256, 0, stream>>>(w_d, wB);
  fa_main_mfma<<<dim3(3072), 256, 0, stream>>>(
      xT, wB, wh_pred, w_off, b_off, b_d, out);
}

// Round 14
// 85.893 us; speedup vs baseline: 1.2673x; 1.2673x over previous
//
#include <hip/hip_runtime.h>

// B=8, G=3, IN=384, OUT=384, H=64, W=64, CG=128, OG=128
// R14: R8 VERBATIM (passed: 87.3us total / 77us main; bf16 xT, validated
// bf16 MFMA layout, parity dbuf, one barrier/tap, fp16 weight table,
// XCD pin) with ONE safe edit: the stage blend is expressed as packed
// fp32 (float2 -> v_pk_mul_f32 / v_pk_fma_f32), 17 -> 13 VALU ops/dword,
// SAME IEEE fp32 fma chain per channel -> bit-identical output to R8.
// fp16-data blend lever abandoned (R9/R10/R13: 3x identical 5.53 failures).

typedef __attribute__((ext_vector_type(8))) short short8;
typedef __attribute__((ext_vector_type(4))) float floatx4;
typedef __attribute__((ext_vector_type(2))) float float2v;
typedef __attribute__((ext_vector_type(4))) unsigned int uintx4;

#define SLAB 524288            // 64*64*128 shorts per (b,g)
#define XT_GUARD 8704          // head guard, shorts (min 8320 needed)
#define XT_TAIL 512            // tail guard; deeper overflow lands in wB (finite, masked)

__device__ __forceinline__ float bf_lo(unsigned int d) {
  return __uint_as_float(d << 16);
}
__device__ __forceinline__ float bf_hi(unsigned int d) {
  return __uint_as_float(d & 0xffff0000u);
}
__device__ __forceinline__ unsigned int cvtpk_bf16(float lo, float hi) {
  unsigned int r;
  asm("v_cvt_pk_bf16_f32 %0, %1, %2" : "=v"(r) : "v"(lo), "v"(hi));
  return r;
}
__device__ __forceinline__ ushort f2h(float x) {
  _Float16 h = (_Float16)x;
  return __builtin_bit_cast(ushort, h);
}
__device__ __forceinline__ float h2f(ushort u) {
  return (float)__builtin_bit_cast(_Float16, u);
}
__device__ __forceinline__ float2v unpk2(unsigned int d) {
  float2v r;
  r[0] = bf_lo(d);
  r[1] = bf_hi(d);
  return r;
}

// ---------------------------------------------------------------------------
// Kernel 1: NCHW fp32 -> (b,g,y,x,c) bf16, c contiguous (128)
// ---------------------------------------------------------------------------
__global__ __launch_bounds__(256) void transpose_x_kernel(
    const float* __restrict__ in, ushort* __restrict__ xT) {
  __shared__ float tile[32][33];
  const int t  = threadIdx.x;
  const int tx = t & 31, ty = t >> 5;      // 32 x 8
  const int bx = blockIdx.x;               // x-tile (2) x c-tile (4)
  const int x0 = (bx & 1) * 32;
  const int c0 = (bx >> 1) * 32;
  const int y  = blockIdx.y;
  const int bg = blockIdx.z;
  const int b  = bg / 3, g = bg % 3;

  const float* src = in + ((size_t)(b * 384 + g * 128)) * 4096 + (size_t)y * 64;
#pragma unroll
  for (int it = 0; it < 4; ++it) {
    int c = c0 + ty + it * 8;
    tile[ty + it * 8][tx] = src[(size_t)c * 4096 + x0 + tx];
  }
  __syncthreads();
  ushort* dst = xT + (((size_t)bg * 64 + y) * 64) * 128;
#pragma unroll
  for (int it = 0; it < 4; ++it) {
    int x = x0 + ty + it * 8;
    float v = tile[tx][ty + it * 8];
    dst[(size_t)x * 128 + c0 + tx] =
        (ushort)((__float_as_uint(v) + 0x8000u) >> 16);
  }
}

// ---------------------------------------------------------------------------
// Kernel 2: w_d (OUT, CG, 3, 3) fp32 -> bf16 A-fragment order (VALIDATED):
//   wB[(((g*9+k)*4+s)*8+f)*64+l][j] = w[g][o=f*16+(l&15)][c=s*32+(l>>4)*8+j]
// ---------------------------------------------------------------------------
__global__ __launch_bounds__(256) void swizzle_w_kernel(
    const float* __restrict__ w_d, ushort* __restrict__ wB) {
  int idx = blockIdx.x * 256 + threadIdx.x;  // 442368 total
  if (idx >= 442368) return;
  int j  = idx & 7;
  int l  = (idx >> 3) & 63;
  int f  = (idx >> 9) & 7;
  int s  = (idx >> 12) & 3;
  int t2 = idx >> 14;            // g*9 + k
  int k  = t2 % 9;
  int g  = t2 / 9;
  int o  = f * 16 + (l & 15);
  int c  = s * 32 + (l >> 4) * 8 + j;
  float v = w_d[((size_t)(g * 128 + o) * 128 + c) * 9 + k];
  wB[idx] = (ushort)((__float_as_uint(v) + 0x8000u) >> 16);
}

// ---------------------------------------------------------------------------
// Kernel 3: main fused kernel. 1536 blocks, XCD-swizzled: b = bid&7.
// Block = (b,g,h): 64 positions x 128 out-chans, 8 waves (512 threads).
// ---------------------------------------------------------------------------
__global__ __launch_bounds__(512) void fa_main_mfma(
    const ushort* __restrict__ xT, const ushort* __restrict__ wB,
    const float* __restrict__ wh_pred, const float* __restrict__ w_off,
    const float* __restrict__ b_off, const float* __restrict__ b_d,
    float* __restrict__ out) {
  __shared__ int     off_s[9][64];
  __shared__ ushort4 w4h_s[9][64];       // fp16 bilinear weights (w00..w11)
  __shared__ ushort  samp[2][64][128];   // bf16, XOR-swizzled: col ^= (pos&7)<<3

  const int t   = threadIdx.x;
  const int bid = blockIdx.x;
  const int b   = bid & 7;          // XCD-pinned batch image
  const int rem = bid >> 3;         // 0..191 = g*64 + h
  const int g   = rem >> 6;
  const int h   = rem & 63;

  // --- prologue: per (tap,pos) bilinear weights + clamped base offset ------
  for (int idx = t; idx < 576; idx += 512) {
    int k = idx >> 6, pos = idx & 63;
    float wh0 = wh_pred[(((size_t)b * 6 + g * 2 + 0) * 64 + h) * 64 + pos];
    float wh1 = wh_pred[(((size_t)b * 6 + g * 2 + 1) * 64 + h) * 64 + pos];
    int oy_i = g * 18 + k * 2;
    int ox_i = oy_i + 1;
    float oy = fmaf(w_off[oy_i * 2], wh0, fmaf(w_off[oy_i * 2 + 1], wh1, b_off[oy_i]));
    float ox = fmaf(w_off[ox_i * 2], wh0, fmaf(w_off[ox_i * 2 + 1], wh1, b_off[ox_i]));
    float py = oy + (float)(h + k / 3 - 1);
    float px = ox + (float)(pos + k % 3 - 1);

    float fy = floorf(py), fx = floorf(px);
    int y0 = (int)fy, x0 = (int)fx;
    float wy = py - fy, wx = px - fx;
    float m_y0 = ((unsigned)y0 < 64u) ? 1.f : 0.f;
    float m_y1 = ((unsigned)(y0 + 1) < 64u) ? 1.f : 0.f;
    float m_x0 = ((unsigned)x0 < 64u) ? 1.f : 0.f;
    float m_x1 = ((unsigned)(x0 + 1) < 64u) ? 1.f : 0.f;
    ushort4 w4;
    w4.x = f2h((1.f - wy) * (1.f - wx) * m_y0 * m_x0);
    w4.y = f2h((1.f - wy) * wx * m_y0 * m_x1);
    w4.z = f2h(wy * (1.f - wx) * m_y1 * m_x0);
    w4.w = f2h(wy * wx * m_y1 * m_x1);
    int y0c = min(max(y0, -1), 63);
    int x0c = min(max(x0, -1), 63);
    off_s[k][pos] = (y0c * 64 + x0c) * 128;
    w4h_s[k][pos] = w4;
  }
  __syncthreads();

  const int wv  = t >> 6;   // wave 0..7
  const int l   = t & 63;
  const int l15 = l & 15;
  const int lhi = l >> 4;   // 0..3

  floatx4 acc[4];
#pragma unroll
  for (int r = 0; r < 4; ++r) {
    float bias = b_d[g * 128 + wv * 16 + lhi * 4 + r];
#pragma unroll
    for (int jb = 0; jb < 4; ++jb) acc[jb][r] = bias;
  }

  // staging: 16 lanes per position (contiguous 16B each), 2 passes of 32 pos
  const int g16    = t >> 4;   // 0..31: position group
  const int lane16 = t & 15;   // 0..15: 16B slice of the 256B corner row
  const ushort* xb = xT + (size_t)(b * 3 + g) * SLAB;
  const ushort* wg = wB + (size_t)g * 9 * 16384;

  // packed-fp32 blend (v_pk_mul_f32/v_pk_fma_f32): same fma chain as R8,
  // applied per channel lane -> bit-identical results, fewer instructions.
  auto stage = [&](int k, ushort(*sb)[128]) {
#pragma unroll
    for (int p = 0; p < 2; ++p) {
      int pos = p * 32 + g16;
      int off = off_s[k][pos];
      ushort4 wq = w4h_s[k][pos];
      float2v W00, W01, W10, W11;
      W00[0] = W00[1] = h2f(wq.x);
      W01[0] = W01[1] = h2f(wq.y);
      W10[0] = W10[1] = h2f(wq.z);
      W11[0] = W11[1] = h2f(wq.w);
      const ushort* p00 = xb + off + lane16 * 8;
      uintx4 a00 = *(const uintx4*)(p00);          // corners: +0,+128,
      uintx4 a01 = *(const uintx4*)(p00 + 128);    //          +8192,+8320
      uintx4 a10 = *(const uintx4*)(p00 + 8192);
      uintx4 a11 = *(const uintx4*)(p00 + 8320);
      uintx4 pk;
#pragma unroll
      for (int d = 0; d < 4; ++d) {
        float2v v = unpk2(a00[d]) * W00;
        v = __builtin_elementwise_fma(unpk2(a01[d]), W01, v);
        v = __builtin_elementwise_fma(unpk2(a10[d]), W10, v);
        v = __builtin_elementwise_fma(unpk2(a11[d]), W11, v);
        pk[d] = cvtpk_bf16(v[0], v[1]);
      }
      *(uintx4*)&sb[pos][(lane16 * 8) ^ ((pos & 7) << 3)] = pk;
    }
  };

  auto mfma_phase = [&](int k, const ushort(*sb)[128]) {
    const ushort* wk = wg + (size_t)k * 16384;
    __builtin_amdgcn_s_setprio(1);
#pragma unroll
    for (int s = 0; s < 4; ++s) {
      short8 a = *(const short8*)(wk + ((s * 8 + wv) * 64 + l) * 8);
      const int cb = (s * 32 + lhi * 8) ^ ((l15 & 7) << 3);
#pragma unroll
      for (int jb = 0; jb < 4; ++jb) {
        short8 bf = *(const short8*)&sb[jb * 16 + l15][cb];
        acc[jb] = __builtin_amdgcn_mfma_f32_16x16x32_bf16(a, bf, acc[jb], 0, 0, 0);
      }
    }
    __builtin_amdgcn_s_setprio(0);
  };

  // --- parity-dbuf tap loop, ONE barrier per tap (R8-proven structure) -----
  stage(0, samp[0]);
  __syncthreads();
  for (int k = 0; k < 9; ++k) {
    if (k < 8) stage(k + 1, samp[(k + 1) & 1]);  // loads fly under mfma(k)
    mfma_phase(k, samp[k & 1]);
    __syncthreads();
  }

  // --- store: out (B, 384, H, W); C col(lane&15) = pos = contiguous W -------
#pragma unroll
  for (int jb = 0; jb < 4; ++jb) {
#pragma unroll
    for (int r = 0; r < 4; ++r) {
      int o = wv * 16 + lhi * 4 + r;
      int pos = jb * 16 + l15;
      out[(((size_t)(b * 384 + g * 128 + o)) * 64 + h) * 64 + pos] = acc[jb][r];
    }
  }
}

extern "C" void kernel_launch(void* const* d_in, const int* in_sizes, int n_in,
                              void* d_out, int out_size, void* d_ws, size_t ws_size,
                              hipStream_t stream) {
  const float* input   = (const float*)d_in[0];
  const float* wh_pred = (const float*)d_in[1];
  const float* w_off   = (const float*)d_in[2];
  const float* b_off   = (const float*)d_in[3];
  const float* w_d     = (const float*)d_in[4];
  const float* b_d     = (const float*)d_in[5];
  float* out = (float*)d_out;

  // layout: [head guard][24 slabs of xT (bf16)][tail guard][wB (bf16)]
  ushort* xT = (ushort*)d_ws + XT_GUARD;            // 24*SLAB shorts = 25.2 MB
  ushort* wB = xT + (size_t)24 * SLAB + XT_TAIL;    // 442368 bf16 = 0.88 MB

  transpose_x_kernel<<<dim3(8, 64, 24), 256, 0, stream>>>(input, xT);
  swizzle_w_kernel<<<dim3(1728), 256, 0, stream>>>(w_d, wB);
  fa_main_mfma<<<dim3(1536), 512, 0, stream>>>(
      xT, wB, wh_pred, w_off, b_off, b_d, out);
}